// Round 8
// baseline (3616.261 us; speedup 1.0000x reference)
//
#include <hip/hip_runtime.h>

typedef __attribute__((ext_vector_type(8)))  short  s16x8;
typedef __attribute__((ext_vector_type(8)))  __bf16 bf16x8;
typedef __attribute__((ext_vector_type(16))) float  f32x16;
typedef __attribute__((ext_vector_type(4)))  unsigned int u32x4;

#define EPSF 1e-36f

static __device__ __forceinline__ f32x16 MFMA(s16x8 a, s16x8 b, f32x16 c) {
  return __builtin_amdgcn_mfma_f32_32x32x16_bf16(
      __builtin_bit_cast(bf16x8, a), __builtin_bit_cast(bf16x8, b), c, 0, 0, 0);
}

static __device__ __forceinline__ short f2bf(float f) {
  unsigned u = __builtin_bit_cast(unsigned, f);
  u = (u + 0x7FFFu + ((u >> 16) & 1u)) >> 16;
  return (short)u;
}

static __device__ __forceinline__ unsigned pkf(float a, float b) {
  return (unsigned)(unsigned short)f2bf(a) | ((unsigned)(unsigned short)f2bf(b) << 16);
}

static __device__ __forceinline__ float bf2f(short s) {
  return __builtin_bit_cast(float, ((unsigned)(unsigned short)s) << 16);
}

// D (C/D layout: col=lane&31, row=(reg&3)+8*(reg>>2)+4h) -> two k-chunk bf16
// operand fragments (slot t of chunk kk = matrix[16kk+8h+t][c31]); in-register
// pack + half-swap via lane^32. PROVEN in R6.
static __device__ __forceinline__ void redistR(const f32x16 d, float sc, int h,
                                               s16x8& f0, s16x8& f1) {
  unsigned pk[8];
#pragma unroll
  for (int q = 0; q < 8; ++q) pk[q] = pkf(d[2 * q] * sc, d[2 * q + 1] * sc);
  unsigned s0 = h ? pk[0] : pk[2];
  unsigned s1 = h ? pk[1] : pk[3];
  unsigned s2 = h ? pk[4] : pk[6];
  unsigned s3 = h ? pk[5] : pk[7];
  unsigned r0 = (unsigned)__shfl_xor((int)s0, 32);
  unsigned r1 = (unsigned)__shfl_xor((int)s1, 32);
  unsigned r2 = (unsigned)__shfl_xor((int)s2, 32);
  unsigned r3 = (unsigned)__shfl_xor((int)s3, 32);
  u32x4 a, b;
  a.x = h ? r0 : pk[0]; a.y = h ? r1 : pk[1]; a.z = h ? pk[2] : r0; a.w = h ? pk[3] : r1;
  b.x = h ? r2 : pk[4]; b.y = h ? r3 : pk[5]; b.z = h ? pk[6] : r2; b.w = h ? pk[7] : r3;
  f0 = __builtin_bit_cast(s16x8, a);
  f1 = __builtin_bit_cast(s16x8, b);
}

// flat step sig in [0,368): 16 groups of (big site: 16 m-steps, 7 small sites: 1 step)
static __device__ __forceinline__ void decodeStep(int sig, int& site, int& m, int& off) {
  int g = sig / 23, o = sig - g * 23;
  if (o < 16) { site = 8 * g; m = o; off = g * 376832 + o * 16384; }
  else { site = 8 * g + (o - 15); m = 0; off = g * 376832 + 262144 + (o - 16) * 16384; }
}

// ---------------- prep: embedding table Em[site][n][16] (f32) ----------------
extern "C" __global__ void prep_emb_k(const float* __restrict__ x, float* __restrict__ Em) {
  int id = blockIdx.x * 256 + threadIdx.x;
  int site = id >> 10, n = id & 1023;
  float x0 = x[(n * 128 + site) * 2 + 0];
  float x1 = x[(n * 128 + site) * 2 + 1];
  const float P5 = 1.57079632679f, P25 = 0.785398163397f, R = 0.70710678118f;
  float u[4] = {sinf(P5 * x0) * R, cosf(P5 * x0) * R, sinf(P25 * x0) * R, cosf(P25 * x0) * R};
  float v[4] = {sinf(P5 * x1) * R, cosf(P5 * x1) * R, sinf(P25 * x1) * R, cosf(P25 * x1) * R};
#pragma unroll
  for (int a = 0; a < 4; ++a) {
    float4 o;
    o.x = u[a] * v[0]; o.y = u[a] * v[1]; o.z = u[a] * v[2]; o.w = u[a] * v[3];
    *(float4*)&Em[id * 16 + a * 4] = o;
  }
}

// ---------------- prep: weights -> As bf16 [m][r][e][l] (+ optional Af f32) ----------------
extern "C" __global__ void prep_w_k(const float* __restrict__ wb, const float* __restrict__ wsm,
                                    short* __restrict__ As, float* __restrict__ Af) {
  int site = blockIdx.x;
  bool big = (site & 7) == 0;
  int nE = big ? 262144 : 16384;
  int nb = (site + 7) >> 3;
  int bs = nb * 262144 + (site - nb) * 16384;
  int kb = site >> 3;
  int ksm = site - kb - 1;
  for (int i = threadIdx.x; i < nE; i += 256) {
    int l = i & 31, e = (i >> 5) & 15, r = (i >> 9) & 31, m = i >> 14;
    float val = big ? wb[(((kb * 32 + l) * 16 + e) * 16 + m) * 32 + r]
                    : wsm[((ksm * 32 + l) * 16 + e) * 32 + r];
    if (site == 0 && l != 0) val = 0.f;
    if (site == 127 && r != 0) val = 0.f;
    As[bs + i] = f2bf(val);
    if (Af) Af[bs + i] = val;
  }
}

// ---------------- B-form: Ball[sigL][n][frag layout] = sum_e er[e] * W[l][e][r] ----------------
// thread (r = tid&31, nsub = tid>>5); block = (sigL, n-octet). Output fragment
// contract (consumer = tn_chain): elem offset (shorts) within a sample's 1024:
//   kk*512 + ((l>>3)&1)*256 + r*8 + (l&7),  value = B[l][r].
extern "C" __global__ void __launch_bounds__(256, 4)
bform_k(const float* __restrict__ Af, const float* __restrict__ Em,
        short* __restrict__ Ball, int s0) {
  const int sigL = blockIdx.x >> 7;
  const int noct = blockIdx.x & 127;
  int site, m, off; decodeStep(s0 + sigL, site, m, off); (void)m;
  const int tid = threadIdx.x;
  const int r = tid & 31;
  const int nsub = tid >> 5;
  const int n = noct * 8 + nsub;

  float er[16];
  {
    const float4* ep = (const float4*)&Em[(site * 1024 + n) * 16];
    float4 q0 = ep[0], q1 = ep[1], q2 = ep[2], q3 = ep[3];
    er[0] = q0.x; er[1] = q0.y; er[2] = q0.z; er[3] = q0.w;
    er[4] = q1.x; er[5] = q1.y; er[6] = q1.z; er[7] = q1.w;
    er[8] = q2.x; er[9] = q2.y; er[10] = q2.z; er[11] = q2.w;
    er[12] = q3.x; er[13] = q3.y; er[14] = q3.z; er[15] = q3.w;
  }

  const float* wp = Af + off + r * 512;   // W[r][e][l], e stride 32, l contiguous
  float acc[4][8];
#pragma unroll
  for (int a = 0; a < 4; ++a)
#pragma unroll
    for (int j = 0; j < 8; ++j) acc[a][j] = 0.f;

#pragma unroll
  for (int e = 0; e < 16; ++e) {
    const float4* wr = (const float4*)(wp + e * 32);
    float4 a0 = wr[0], a1 = wr[1], a2 = wr[2], a3 = wr[3];
    float4 a4 = wr[4], a5 = wr[5], a6 = wr[6], a7 = wr[7];
    const float ce = er[e];
    acc[0][0] = fmaf(ce, a0.x, acc[0][0]); acc[0][1] = fmaf(ce, a0.y, acc[0][1]);
    acc[0][2] = fmaf(ce, a0.z, acc[0][2]); acc[0][3] = fmaf(ce, a0.w, acc[0][3]);
    acc[0][4] = fmaf(ce, a1.x, acc[0][4]); acc[0][5] = fmaf(ce, a1.y, acc[0][5]);
    acc[0][6] = fmaf(ce, a1.z, acc[0][6]); acc[0][7] = fmaf(ce, a1.w, acc[0][7]);
    acc[1][0] = fmaf(ce, a2.x, acc[1][0]); acc[1][1] = fmaf(ce, a2.y, acc[1][1]);
    acc[1][2] = fmaf(ce, a2.z, acc[1][2]); acc[1][3] = fmaf(ce, a2.w, acc[1][3]);
    acc[1][4] = fmaf(ce, a3.x, acc[1][4]); acc[1][5] = fmaf(ce, a3.y, acc[1][5]);
    acc[1][6] = fmaf(ce, a3.z, acc[1][6]); acc[1][7] = fmaf(ce, a3.w, acc[1][7]);
    acc[2][0] = fmaf(ce, a4.x, acc[2][0]); acc[2][1] = fmaf(ce, a4.y, acc[2][1]);
    acc[2][2] = fmaf(ce, a4.z, acc[2][2]); acc[2][3] = fmaf(ce, a4.w, acc[2][3]);
    acc[2][4] = fmaf(ce, a5.x, acc[2][4]); acc[2][5] = fmaf(ce, a5.y, acc[2][5]);
    acc[2][6] = fmaf(ce, a5.z, acc[2][6]); acc[2][7] = fmaf(ce, a5.w, acc[2][7]);
    acc[3][0] = fmaf(ce, a6.x, acc[3][0]); acc[3][1] = fmaf(ce, a6.y, acc[3][1]);
    acc[3][2] = fmaf(ce, a6.z, acc[3][2]); acc[3][3] = fmaf(ce, a6.w, acc[3][3]);
    acc[3][4] = fmaf(ce, a7.x, acc[3][4]); acc[3][5] = fmaf(ce, a7.y, acc[3][5]);
    acc[3][6] = fmaf(ce, a7.z, acc[3][6]); acc[3][7] = fmaf(ce, a7.w, acc[3][7]);
  }

  short* bp = Ball + ((size_t)sigL * 1024 + n) * 1024;
#pragma unroll
  for (int loct = 0; loct < 4; ++loct) {   // l0 = loct*8: kk = loct>>1, h' = loct&1
    s16x8 o;
#pragma unroll
    for (int j = 0; j < 8; ++j) o[j] = f2bf(acc[loct][j]);
    *(s16x8*)(bp + (loct >> 1) * 512 + (loct & 1) * 256 + r * 8) = o;
  }
}

// ---------------- chain: blocks 0..255 = samples (4/block), block 256 = partition ----------------
extern "C" __global__ void __launch_bounds__(256, 2)
tn_chain(const short* __restrict__ As, const short* __restrict__ Ball,
         unsigned* __restrict__ CkU, float* __restrict__ LN,
         float* __restrict__ out, int s0, int s1) {
  __shared__ __align__(16) float red[4 * 1056];
  const int tid = threadIdx.x;
  const int lane = tid & 63;
  const int w = tid >> 6;
  const int c31 = lane & 31;
  const int h = lane >> 5;
  const f32x16 Z = {0.f,0.f,0.f,0.f,0.f,0.f,0.f,0.f,0.f,0.f,0.f,0.f,0.f,0.f,0.f,0.f};
  const int nsig = s1 - s0;

  s16x8 Mf0 = {0,0,0,0,0,0,0,0}, Mf1 = {0,0,0,0,0,0,0,0};
  f32x16 Macc = Z;
  float log_norm = 0.f;

  if (blockIdx.x < 256) {
    // ===== sample chains: wave = sample; pure fragment-stream, no LDS =====
    const int n = blockIdx.x * 4 + w;
    if (s0 == 0) {
      if (lane == 0) Mf0[0] = (short)0x3F80;
    } else {
      const unsigned* cp = CkU + ((size_t)n * 64 + lane) * 8;
      u32x4 a = *(const u32x4*)cp;
      u32x4 b = *(const u32x4*)(cp + 4);
      Mf0 = __builtin_bit_cast(s16x8, a);
      Mf1 = __builtin_bit_cast(s16x8, b);
      log_norm = LN[n];
    }

    const short* bb = Ball + (size_t)n * 1024 + lane * 8;
    s16x8 c0, c1, d0, d1, e0, e1;
    {
      const short* p0 = bb;
      c0 = *(const s16x8*)p0; c1 = *(const s16x8*)(p0 + 512);
      const short* p1 = bb + ((size_t)1 << 20);
      d0 = *(const s16x8*)p1; d1 = *(const s16x8*)(p1 + 512);
      const short* p2 = bb + ((size_t)2 << 20);
      e0 = *(const s16x8*)p2; e1 = *(const s16x8*)(p2 + 512);
    }

#pragma unroll 1
    for (int k = 0; k < nsig; ++k) {
      int site, m, off; decodeStep(s0 + k, site, m, off); (void)off;
      f32x16 D1 = MFMA(Mf0, c0, Z);
      D1 = MFMA(Mf1, c1, D1);
      s16x8 Cf0, Cf1;
      redistR(D1, 1.f, h, Cf0, Cf1);
      if (m == 0) Macc = Z;
      Macc = MFMA(c0, Cf0, Macc);
      Macc = MFMA(c1, Cf1, Macc);

      bool lastM = (m == (((site & 7) == 0) ? 15 : 0));
      if (lastM) {
        if (site < 127) {
          float s = fabsf(Macc[0]);
#pragma unroll
          for (int j = 1; j < 16; ++j) s = fmaxf(s, fabsf(Macc[j]));
#pragma unroll
          for (int off2 = 32; off2 >= 1; off2 >>= 1) s = fmaxf(s, __shfl_xor(s, off2));
          float inv = 1.f / (s + EPSF);
          log_norm += logf(s + EPSF);
          redistR(Macc, inv, h, Mf0, Mf1);
        } else {
          if (lane == 0) out[n] = logf(fmaxf(Macc[0], 0.f) + EPSF) + log_norm;
        }
      }
      c0 = d0; c1 = d1; d0 = e0; d1 = e1;
      if (k + 3 < nsig) {
        const short* p = bb + ((size_t)(k + 3) << 20);
        e0 = *(const s16x8*)p;
        e1 = *(const s16x8*)(p + 512);
      }
    }
    if (s1 < 368) {
      unsigned* cp = CkU + ((size_t)n * 64 + lane) * 8;
      *(u32x4*)cp       = __builtin_bit_cast(u32x4, Mf0);
      *(u32x4*)(cp + 4) = __builtin_bit_cast(u32x4, Mf1);
      if (lane == 0) LN[n] = log_norm;
    }
  } else {
    // ===== partition chain (log_Z): 1 block, 4 waves x 4 e each =====
    if (s0 == 0) {
      if (lane == 0) Mf0[0] = (short)0x3F80;
    } else {
      const unsigned* cp = CkU + ((size_t)1024 * 64 + lane) * 8;
      u32x4 a = *(const u32x4*)cp;
      u32x4 b = *(const u32x4*)(cp + 4);
      Mf0 = __builtin_bit_cast(s16x8, a);
      Mf1 = __builtin_bit_cast(s16x8, b);
      log_norm = LN[1024];
    }
#pragma unroll 1
    for (int sig = s0; sig < s1; ++sig) {
      int site, m, off; decodeStep(sig, site, m, off);
      if (m == 0) Macc = Z;
      s16x8 pa[4], pb[4];
#pragma unroll
      for (int q = 0; q < 4; ++q) {
        int e = 4 * w + q;
        const short* ap = As + off + (c31 * 16 + e) * 32;
        pa[q] = *(const s16x8*)(ap + 8 * h);
        pb[q] = *(const s16x8*)(ap + 16 + 8 * h);
      }
#pragma unroll
      for (int q = 0; q < 4; ++q) {
        f32x16 D1 = MFMA(Mf0, pa[q], Z);
        D1 = MFMA(Mf1, pb[q], D1);
        s16x8 Cf0, Cf1;
        redistR(D1, 1.f, h, Cf0, Cf1);
        Macc = MFMA(pa[q], Cf0, Macc);
        Macc = MFMA(pb[q], Cf1, Macc);
      }
      bool lastM = (m == (((site & 7) == 0) ? 15 : 0));
      if (lastM) {
        float* myr = red + w * 1056;
#pragma unroll
        for (int reg = 0; reg < 16; ++reg) {
          int row = (reg & 3) + 8 * (reg >> 2) + 4 * h;
          myr[row * 33 + c31] = Macc[reg];
        }
        __syncthreads();
        f32x16 tot;
#pragma unroll
        for (int reg = 0; reg < 16; ++reg) {
          int row = (reg & 3) + 8 * (reg >> 2) + 4 * h;
          int idx = row * 33 + c31;
          tot[reg] = red[idx] + red[1056 + idx] + red[2112 + idx] + red[3168 + idx];
        }
        float s = fabsf(tot[0]);
#pragma unroll
        for (int j = 1; j < 16; ++j) s = fmaxf(s, fabsf(tot[j]));
#pragma unroll
        for (int off2 = 32; off2 >= 1; off2 >>= 1) s = fmaxf(s, __shfl_xor(s, off2));
        __syncthreads();
        if (site < 127) {
          float inv = 1.f / (s + EPSF);
          log_norm += logf(s + EPSF);
          redistR(tot, inv, h, Mf0, Mf1);
        } else {
          if (tid == 0) out[1024] = logf(fmaxf(tot[0], 0.f) + EPSF) + log_norm;
        }
      }
    }
    if (s1 < 368 && w == 0) {
      unsigned* cp = CkU + ((size_t)1024 * 64 + lane) * 8;
      *(u32x4*)cp       = __builtin_bit_cast(u32x4, Mf0);
      *(u32x4*)(cp + 4) = __builtin_bit_cast(u32x4, Mf1);
      if (lane == 0) LN[1024] = log_norm;
    }
  }
}

// ---------------- R6 monolithic fallback (proven) for small ws ----------------
extern "C" __global__ void __launch_bounds__(256, 2)
tn_main_mono(const short* __restrict__ As, const float* __restrict__ Em, float* __restrict__ out) {
  __shared__ __align__(16) char smem[65536];
  const int tid = threadIdx.x;
  const int lane = tid & 63;
  const int w = tid >> 6;
  const int c31 = lane & 31;
  const int h = lane >> 5;
  const f32x16 Z = {0.f,0.f,0.f,0.f,0.f,0.f,0.f,0.f,0.f,0.f,0.f,0.f,0.f,0.f,0.f,0.f};
  s16x8 Mf0 = {0,0,0,0,0,0,0,0}, Mf1 = {0,0,0,0,0,0,0,0};
  if (lane == 0) Mf0[0] = (short)0x3F80;
  f32x16 Macc = Z;
  float log_norm = 0.f;

  if (blockIdx.x < 256) {
    const int n = blockIdx.x * 4 + w;
    float er[16];
    {
      const short* src = As;
#pragma unroll
      for (int k = 0; k < 8; ++k) {
        s16x8 v = *(const s16x8*)(src + (k * 256 + tid) * 8);
        int G = k * 256 + tid, r = G >> 6, p = G & 63;
        *(s16x8*)(smem + (r * 64 + (p ^ (r & 7))) * 16) = v;
      }
    }
    __syncthreads();
#pragma unroll 1
    for (int sig = 0; sig < 368; ++sig) {
      int site, m, off; decodeStep(sig, site, m, off); (void)off;
      char* cur = smem + ((sig & 1) << 15);
      char* nxt = smem + (((sig + 1) & 1) << 15);
      s16x8 pre[8];
      const bool hasNext = (sig + 1 < 368);
      if (hasNext) {
        int st2, m2, off2; decodeStep(sig + 1, st2, m2, off2);
        const short* src = As + off2;
#pragma unroll
        for (int k = 0; k < 8; ++k) pre[k] = *(const s16x8*)(src + (k * 256 + tid) * 8);
      }
      if (m == 0) {
        const float4* ep = (const float4*)&Em[(site * 1024 + n) * 16];
        float4 q0 = ep[0], q1 = ep[1], q2 = ep[2], q3 = ep[3];
        er[0] = q0.x; er[1] = q0.y; er[2] = q0.z; er[3] = q0.w;
        er[4] = q1.x; er[5] = q1.y; er[6] = q1.z; er[7] = q1.w;
        er[8] = q2.x; er[9] = q2.y; er[10] = q2.z; er[11] = q2.w;
        er[12] = q3.x; er[13] = q3.y; er[14] = q3.z; er[15] = q3.w;
      }
      float acc[16];
#pragma unroll
      for (int c = 0; c < 16; ++c) acc[c] = 0.f;
      {
        const char* rowp = cur + c31 * 1024;
        const int sw = (c31 & 7) << 4;
#pragma unroll
        for (int e = 0; e < 16; ++e) {
          s16x8 v0 = *(const s16x8*)(rowp + (((e * 4 + 2 * h + 0) << 4) ^ sw));
          s16x8 v1 = *(const s16x8*)(rowp + (((e * 4 + 2 * h + 1) << 4) ^ sw));
          const float ce = er[e];
#pragma unroll
          for (int c = 0; c < 8; ++c) {
            acc[c]     = fmaf(ce, bf2f(v0[c]), acc[c]);
            acc[8 + c] = fmaf(ce, bf2f(v1[c]), acc[8 + c]);
          }
        }
      }
      s16x8 Bf0, Bf1;
      {
        unsigned o0[4], o1[4];
        o0[0] = pkf(acc[0], acc[1]);   o0[1] = pkf(acc[2], acc[3]);
        o0[2] = pkf(acc[4], acc[5]);   o0[3] = pkf(acc[6], acc[7]);
        o1[0] = pkf(acc[8], acc[9]);   o1[1] = pkf(acc[10], acc[11]);
        o1[2] = pkf(acc[12], acc[13]); o1[3] = pkf(acc[14], acc[15]);
        u32x4 b0, b1;
#pragma unroll
        for (int q = 0; q < 4; ++q) {
          unsigned snd = h ? o0[q] : o1[q];
          unsigned rcv = (unsigned)__shfl_xor((int)snd, 32);
          ((unsigned*)&b0)[q] = h ? rcv : o0[q];
          ((unsigned*)&b1)[q] = h ? o1[q] : rcv;
        }
        Bf0 = __builtin_bit_cast(s16x8, b0);
        Bf1 = __builtin_bit_cast(s16x8, b1);
      }
      f32x16 D1 = MFMA(Mf0, Bf0, Z);
      D1 = MFMA(Mf1, Bf1, D1);
      s16x8 Cf0, Cf1;
      redistR(D1, 1.f, h, Cf0, Cf1);
      if (m == 0) Macc = Z;
      Macc = MFMA(Bf0, Cf0, Macc);
      Macc = MFMA(Bf1, Cf1, Macc);
      bool lastM = (m == (((site & 7) == 0) ? 15 : 0));
      if (lastM) {
        if (site < 127) {
          float s = fabsf(Macc[0]);
#pragma unroll
          for (int j = 1; j < 16; ++j) s = fmaxf(s, fabsf(Macc[j]));
#pragma unroll
          for (int off2 = 32; off2 >= 1; off2 >>= 1) s = fmaxf(s, __shfl_xor(s, off2));
          float inv = 1.f / (s + EPSF);
          log_norm += logf(s + EPSF);
          redistR(Macc, inv, h, Mf0, Mf1);
        } else {
          if (lane == 0) out[n] = logf(fmaxf(Macc[0], 0.f) + EPSF) + log_norm;
        }
      }
      if (hasNext) {
#pragma unroll
        for (int k = 0; k < 8; ++k) {
          int G = k * 256 + tid, r = G >> 6, p = G & 63;
          *(s16x8*)(nxt + (r * 64 + (p ^ (r & 7))) * 16) = pre[k];
        }
      }
      __syncthreads();
    }
  } else {
    float* red = (float*)smem;
#pragma unroll 1
    for (int sig = 0; sig < 368; ++sig) {
      int site, m, off; decodeStep(sig, site, m, off);
      if (m == 0) Macc = Z;
      s16x8 pa[4], pb[4];
#pragma unroll
      for (int q = 0; q < 4; ++q) {
        int e = 4 * w + q;
        const short* ap = As + off + (c31 * 16 + e) * 32;
        pa[q] = *(const s16x8*)(ap + 8 * h);
        pb[q] = *(const s16x8*)(ap + 16 + 8 * h);
      }
#pragma unroll
      for (int q = 0; q < 4; ++q) {
        f32x16 D1 = MFMA(Mf0, pa[q], Z);
        D1 = MFMA(Mf1, pb[q], D1);
        s16x8 Cf0, Cf1;
        redistR(D1, 1.f, h, Cf0, Cf1);
        Macc = MFMA(pa[q], Cf0, Macc);
        Macc = MFMA(pb[q], Cf1, Macc);
      }
      bool lastM = (m == (((site & 7) == 0) ? 15 : 0));
      if (lastM) {
        float* myr = red + w * 1056;
#pragma unroll
        for (int reg = 0; reg < 16; ++reg) {
          int row = (reg & 3) + 8 * (reg >> 2) + 4 * h;
          myr[row * 33 + c31] = Macc[reg];
        }
        __syncthreads();
        f32x16 tot;
#pragma unroll
        for (int reg = 0; reg < 16; ++reg) {
          int row = (reg & 3) + 8 * (reg >> 2) + 4 * h;
          int idx = row * 33 + c31;
          tot[reg] = red[idx] + red[1056 + idx] + red[2112 + idx] + red[3168 + idx];
        }
        float s = fabsf(tot[0]);
#pragma unroll
        for (int j = 1; j < 16; ++j) s = fmaxf(s, fabsf(tot[j]));
#pragma unroll
        for (int off2 = 32; off2 >= 1; off2 >>= 1) s = fmaxf(s, __shfl_xor(s, off2));
        __syncthreads();
        if (site < 127) {
          float inv = 1.f / (s + EPSF);
          log_norm += logf(s + EPSF);
          redistR(tot, inv, h, Mf0, Mf1);
        } else {
          if (tid == 0) out[1024] = logf(fmaxf(tot[0], 0.f) + EPSF) + log_norm;
        }
      }
    }
  }
}

extern "C" void kernel_launch(void* const* d_in, const int* in_sizes, int n_in,
                              void* d_out, int out_size, void* d_ws, size_t ws_size,
                              hipStream_t stream) {
  (void)in_sizes; (void)n_in; (void)out_size;
  const float* x   = (const float*)d_in[0];
  const float* wb  = (const float*)d_in[1];
  const float* wsm = (const float*)d_in[2];
  char* ws = (char*)d_ws;
  float* out = (float*)d_out;
  short* As = (short*)ws;                               // 12,058,624 B

  // pick window count: Ball = (368/nwin)*1024*2048 B after 47,185,920 B of fixed buffers
  int nwin = 0;
  const size_t fixed = 47185920ull;
  for (int c = 4; c <= 16; c *= 2) {
    if (ws_size >= fixed + (size_t)(368 / c) * 1024 * 2048) { nwin = c; break; }
  }

  if (nwin) {
    float*    Af   = (float*)(ws + 12058624);           // 24,117,248 B
    float*    Em   = (float*)(ws + 36175872);           //  8,388,608 B
    unsigned* CkU  = (unsigned*)(ws + 44564480);        //  2,099,200 B
    float*    LN   = (float*)(ws + 46663680);           //      4,100 B
    short*    Ball = (short*)(ws + 47185920);
    prep_emb_k<<<512, 256, 0, stream>>>(x, Em);
    prep_w_k<<<128, 256, 0, stream>>>(wb, wsm, As, Af);
    const int spw = 368 / nwin;                          // sigs per window (multiple of 23)
    for (int wdx = 0; wdx < nwin; ++wdx) {
      const int s0 = wdx * spw;
      bform_k<<<spw * 128, 256, 0, stream>>>(Af, Em, Ball, s0);
      tn_chain<<<257, 256, 0, stream>>>(As, Ball, CkU, LN, out, s0, s0 + spw);
    }
  } else {
    float* Em = (float*)(ws + 12058624);
    prep_emb_k<<<512, 256, 0, stream>>>(x, Em);
    prep_w_k<<<128, 256, 0, stream>>>(wb, wsm, As, nullptr);
    tn_main_mono<<<257, 256, 0, stream>>>(As, Em, out);
  }
}

// Round 9
// 3571.754 us; speedup vs baseline: 1.0125x; 1.0125x over previous
//
#include <hip/hip_runtime.h>

typedef __attribute__((ext_vector_type(8)))  short  s16x8;
typedef __attribute__((ext_vector_type(8)))  __bf16 bf16x8;
typedef __attribute__((ext_vector_type(16))) float  f32x16;
typedef __attribute__((ext_vector_type(4)))  unsigned int u32x4;

#define EPSF 1e-36f

static __device__ __forceinline__ f32x16 MFMA(s16x8 a, s16x8 b, f32x16 c) {
  return __builtin_amdgcn_mfma_f32_32x32x16_bf16(
      __builtin_bit_cast(bf16x8, a), __builtin_bit_cast(bf16x8, b), c, 0, 0, 0);
}

static __device__ __forceinline__ short f2bf(float f) {
  unsigned u = __builtin_bit_cast(unsigned, f);
  u = (u + 0x7FFFu + ((u >> 16) & 1u)) >> 16;
  return (short)u;
}

static __device__ __forceinline__ unsigned pkf(float a, float b) {
  return (unsigned)(unsigned short)f2bf(a) | ((unsigned)(unsigned short)f2bf(b) << 16);
}

// D (C/D layout: col=lane&31, row=(reg&3)+8*(reg>>2)+4h) -> two k-chunk bf16
// operand fragments (slot t of chunk kk = matrix[16kk+8h+t][c31]); in-register
// pack + half-swap via lane^32. PROVEN R6/R8.
static __device__ __forceinline__ void redistR(const f32x16 d, float sc, int h,
                                               s16x8& f0, s16x8& f1) {
  unsigned pk[8];
#pragma unroll
  for (int q = 0; q < 8; ++q) pk[q] = pkf(d[2 * q] * sc, d[2 * q + 1] * sc);
  unsigned s0 = h ? pk[0] : pk[2];
  unsigned s1 = h ? pk[1] : pk[3];
  unsigned s2 = h ? pk[4] : pk[6];
  unsigned s3 = h ? pk[5] : pk[7];
  unsigned r0 = (unsigned)__shfl_xor((int)s0, 32);
  unsigned r1 = (unsigned)__shfl_xor((int)s1, 32);
  unsigned r2 = (unsigned)__shfl_xor((int)s2, 32);
  unsigned r3 = (unsigned)__shfl_xor((int)s3, 32);
  u32x4 a, b;
  a.x = h ? r0 : pk[0]; a.y = h ? r1 : pk[1]; a.z = h ? pk[2] : r0; a.w = h ? pk[3] : r1;
  b.x = h ? r2 : pk[4]; b.y = h ? r3 : pk[5]; b.z = h ? pk[6] : r2; b.w = h ? pk[7] : r3;
  f0 = __builtin_bit_cast(s16x8, a);
  f1 = __builtin_bit_cast(s16x8, b);
}

// flat step sig in [0,368): 16 groups of (big site: 16 m-steps, 7 small sites: 1 step)
static __device__ __forceinline__ void decodeStep(int sig, int& site, int& m, int& off) {
  int g = sig / 23, o = sig - g * 23;
  if (o < 16) { site = 8 * g; m = o; off = g * 376832 + o * 16384; }
  else { site = 8 * g + (o - 15); m = 0; off = g * 376832 + 262144 + (o - 16) * 16384; }
}

// ---------------- prep: embedding table Em[site][n][16] (f32) ----------------
extern "C" __global__ void prep_emb_k(const float* __restrict__ x, float* __restrict__ Em) {
  int id = blockIdx.x * 256 + threadIdx.x;
  int site = id >> 10, n = id & 1023;
  float x0 = x[(n * 128 + site) * 2 + 0];
  float x1 = x[(n * 128 + site) * 2 + 1];
  const float P5 = 1.57079632679f, P25 = 0.785398163397f, R = 0.70710678118f;
  float u[4] = {sinf(P5 * x0) * R, cosf(P5 * x0) * R, sinf(P25 * x0) * R, cosf(P25 * x0) * R};
  float v[4] = {sinf(P5 * x1) * R, cosf(P5 * x1) * R, sinf(P25 * x1) * R, cosf(P25 * x1) * R};
#pragma unroll
  for (int a = 0; a < 4; ++a) {
    float4 o;
    o.x = u[a] * v[0]; o.y = u[a] * v[1]; o.z = u[a] * v[2]; o.w = u[a] * v[3];
    *(float4*)&Em[id * 16 + a * 4] = o;
  }
}

// ---------------- prep: weights -> As bf16 + Af f32, layout [m][r][e][l] ----------------
extern "C" __global__ void prep_w_k(const float* __restrict__ wb, const float* __restrict__ wsm,
                                    short* __restrict__ As, float* __restrict__ Af) {
  int site = blockIdx.x;
  bool big = (site & 7) == 0;
  int nE = big ? 262144 : 16384;
  int nb = (site + 7) >> 3;
  int bs = nb * 262144 + (site - nb) * 16384;
  int kb = site >> 3;
  int ksm = site - kb - 1;
  for (int i = threadIdx.x; i < nE; i += 256) {
    int l = i & 31, e = (i >> 5) & 15, r = (i >> 9) & 31, m = i >> 14;
    float val = big ? wb[(((kb * 32 + l) * 16 + e) * 16 + m) * 32 + r]
                    : wsm[((ksm * 32 + l) * 16 + e) * 32 + r];
    if (site == 0 && l != 0) val = 0.f;
    if (site == 127 && r != 0) val = 0.f;
    As[bs + i] = f2bf(val);
    Af[bs + i] = val;
  }
}

// ---------------- fused main: blocks 0..255 = 4 samples (4 consumer + 4 producer waves),
//                  block 256 = partition (8 waves x 2 e) ----------------
extern "C" __global__ void __launch_bounds__(512, 4)
tn_fused(const short* __restrict__ As, const float* __restrict__ Af,
         const float* __restrict__ Em, float* __restrict__ out) {
  // chain blocks: 2 x (4 samples x 2 frags x 1KB) dbuf = 32KB
  // partition block: partials [2 parity][8 waves][1056 f32] = 67.5KB
  __shared__ __align__(16) char smem[67584];
  const int tid = threadIdx.x;
  const int lane = tid & 63;
  const int w = tid >> 6;
  const int c31 = lane & 31;
  const int h = lane >> 5;
  const f32x16 Z = {0.f,0.f,0.f,0.f,0.f,0.f,0.f,0.f,0.f,0.f,0.f,0.f,0.f,0.f,0.f,0.f};

  if (blockIdx.x < 256) {
    if (w < 4) {
      // ===================== CONSUMER: chain for sample n =====================
      const int n = blockIdx.x * 4 + w;
      s16x8 Mf0 = {0,0,0,0,0,0,0,0}, Mf1 = {0,0,0,0,0,0,0,0};
      if (lane == 0) Mf0[0] = (short)0x3F80;   // M_init = e0 e0^T
      f32x16 Macc = Z;
      float log_norm = 0.f;

      __syncthreads();   // prologue: producers fill buf0
#pragma unroll 1
      for (int sig = 0; sig < 368; ++sig) {
        int site, m, off; decodeStep(sig, site, m, off); (void)off;
        const char* src = smem + ((sig & 1) << 14) + w * 4096 + lane * 16;
        s16x8 c0 = *(const s16x8*)src;
        s16x8 c1 = *(const s16x8*)(src + 1024);

        f32x16 D1 = MFMA(Mf0, c0, Z);
        D1 = MFMA(Mf1, c1, D1);
        s16x8 Cf0, Cf1;
        redistR(D1, 1.f, h, Cf0, Cf1);
        if (m == 0) Macc = Z;
        Macc = MFMA(c0, Cf0, Macc);
        Macc = MFMA(c1, Cf1, Macc);

        bool lastM = (m == (((site & 7) == 0) ? 15 : 0));
        if (lastM) {
          if (site < 127) {
            float s = fabsf(Macc[0]);
#pragma unroll
            for (int j = 1; j < 16; ++j) s = fmaxf(s, fabsf(Macc[j]));
#pragma unroll
            for (int off2 = 32; off2 >= 1; off2 >>= 1) s = fmaxf(s, __shfl_xor(s, off2));
            float inv = 1.f / (s + EPSF);
            log_norm += logf(s + EPSF);
            redistR(Macc, inv, h, Mf0, Mf1);
          } else {
            if (lane == 0) out[n] = logf(fmaxf(Macc[0], 0.f) + EPSF) + log_norm;
          }
        }
        __syncthreads();   // step boundary
      }
    } else {
      // ===================== PRODUCER: B(sig+1) for sample (w-4) =====================
      const int n = blockIdx.x * 4 + (w - 4);
      char* const myslot = smem + (w - 4) * 4096 + lane * 16;
      float er[16];

      // body for one target step sigN (writes buf[sigN&1])
      auto produce = [&](int sigN) {
        int st, m, off; decodeStep(sigN, st, m, off);
        if (m == 0) {
          const float4* ep = (const float4*)&Em[(st * 1024 + n) * 16];
          float4 q0 = ep[0], q1 = ep[1], q2 = ep[2], q3 = ep[3];
          er[0] = q0.x; er[1] = q0.y; er[2] = q0.z; er[3] = q0.w;
          er[4] = q1.x; er[5] = q1.y; er[6] = q1.z; er[7] = q1.w;
          er[8] = q2.x; er[9] = q2.y; er[10] = q2.z; er[11] = q2.w;
          er[12] = q3.x; er[13] = q3.y; er[14] = q3.z; er[15] = q3.w;
        }
        // B[l=16h+c][r=c31] = sum_e er[e] * W[l][e][r];  Af[m][r][e][l] f32
        const float* wp = Af + off + c31 * 512 + h * 16;
        float acc[16];
#pragma unroll
        for (int c = 0; c < 16; ++c) acc[c] = 0.f;
#pragma unroll
        for (int e = 0; e < 16; ++e) {
          float av[16];
          *(float4*)&av[0]  = *(const float4*)(wp + e * 32 + 0);
          *(float4*)&av[4]  = *(const float4*)(wp + e * 32 + 4);
          *(float4*)&av[8]  = *(const float4*)(wp + e * 32 + 8);
          *(float4*)&av[12] = *(const float4*)(wp + e * 32 + 12);
          const float ce = er[e];
#pragma unroll
          for (int c = 0; c < 16; ++c) acc[c] = fmaf(ce, av[c], acc[c]);
        }
        // pack + half-swap -> fragments (R6-proven path)
        unsigned o0[4], o1[4];
        o0[0] = pkf(acc[0], acc[1]);   o0[1] = pkf(acc[2], acc[3]);
        o0[2] = pkf(acc[4], acc[5]);   o0[3] = pkf(acc[6], acc[7]);
        o1[0] = pkf(acc[8], acc[9]);   o1[1] = pkf(acc[10], acc[11]);
        o1[2] = pkf(acc[12], acc[13]); o1[3] = pkf(acc[14], acc[15]);
        u32x4 b0, b1;
#pragma unroll
        for (int q = 0; q < 4; ++q) {
          unsigned snd = h ? o0[q] : o1[q];
          unsigned rcv = (unsigned)__shfl_xor((int)snd, 32);
          ((unsigned*)&b0)[q] = h ? rcv : o0[q];
          ((unsigned*)&b1)[q] = h ? o1[q] : rcv;
        }
        char* dst = myslot + ((sigN & 1) << 14);
        *(s16x8*)dst          = __builtin_bit_cast(s16x8, b0);
        *(s16x8*)(dst + 1024) = __builtin_bit_cast(s16x8, b1);
      };

      produce(0);          // prologue fill buf0
      __syncthreads();
#pragma unroll 1
      for (int sig = 0; sig < 368; ++sig) {
        if (sig + 1 < 368) produce(sig + 1);
        __syncthreads();   // step boundary
      }
    }
  } else {
    // ===================== PARTITION (log_Z): 8 waves x 2 e =====================
    float* part = (float*)smem;   // [parity][wave][1056]
    s16x8 Mf0 = {0,0,0,0,0,0,0,0}, Mf1 = {0,0,0,0,0,0,0,0};
    if (lane == 0) Mf0[0] = (short)0x3F80;
    f32x16 Pacc = Z;
    float log_norm = 0.f;

    __syncthreads();   // match nothing; own schedule (block-local barriers)
#pragma unroll 1
    for (int sig = 0; sig < 368; ++sig) {
      int site, m, off; decodeStep(sig, site, m, off);
      if (m == 0) Pacc = Z;
#pragma unroll
      for (int q = 0; q < 2; ++q) {
        int e = 2 * w + q;
        const short* ap = As + off + (c31 * 16 + e) * 32;
        s16x8 pa = *(const s16x8*)(ap + 8 * h);
        s16x8 pb = *(const s16x8*)(ap + 16 + 8 * h);
        f32x16 D1 = MFMA(Mf0, pa, Z);
        D1 = MFMA(Mf1, pb, D1);
        s16x8 Cf0, Cf1;
        redistR(D1, 1.f, h, Cf0, Cf1);
        Pacc = MFMA(pa, Cf0, Pacc);
        Pacc = MFMA(pb, Cf1, Pacc);
      }
      bool lastM = (m == (((site & 7) == 0) ? 15 : 0));
      if (lastM) {
        float* myr = part + ((site & 1) * 8 + w) * 1056;
#pragma unroll
        for (int reg = 0; reg < 16; ++reg) {
          int row = (reg & 3) + 8 * (reg >> 2) + 4 * h;
          myr[row * 33 + c31] = Pacc[reg];
        }
      }
      __syncthreads();   // one barrier per sig (uniform)
      if (lastM) {
        const float* base = part + (site & 1) * 8 * 1056;
        f32x16 tot;
#pragma unroll
        for (int reg = 0; reg < 16; ++reg) {
          int row = (reg & 3) + 8 * (reg >> 2) + 4 * h;
          int idx = row * 33 + c31;
          float sum = 0.f;
#pragma unroll
          for (int w2 = 0; w2 < 8; ++w2) sum += base[w2 * 1056 + idx];
          tot[reg] = sum;
        }
        if (site < 127) {
          float s = fabsf(tot[0]);
#pragma unroll
          for (int j = 1; j < 16; ++j) s = fmaxf(s, fabsf(tot[j]));
#pragma unroll
          for (int off2 = 32; off2 >= 1; off2 >>= 1) s = fmaxf(s, __shfl_xor(s, off2));
          float inv = 1.f / (s + EPSF);
          log_norm += logf(s + EPSF);
          redistR(tot, inv, h, Mf0, Mf1);
        } else {
          if (tid == 0) out[1024] = logf(fmaxf(tot[0], 0.f) + EPSF) + log_norm;
        }
      }
    }
  }
}

extern "C" void kernel_launch(void* const* d_in, const int* in_sizes, int n_in,
                              void* d_out, int out_size, void* d_ws, size_t ws_size,
                              hipStream_t stream) {
  (void)in_sizes; (void)n_in; (void)out_size; (void)ws_size;
  const float* x   = (const float*)d_in[0];
  const float* wb  = (const float*)d_in[1];
  const float* wsm = (const float*)d_in[2];
  char* ws = (char*)d_ws;
  short* As = (short*)ws;                          // 12,058,624 B
  float* Af = (float*)(ws + 12058624);             // 24,117,248 B
  float* Em = (float*)(ws + 36175872);             //  8,388,608 B
  float* out = (float*)d_out;                      // 1024 logits + log_Z

  prep_emb_k<<<512, 256, 0, stream>>>(x, Em);
  prep_w_k<<<128, 256, 0, stream>>>(wb, wsm, As, Af);
  tn_fused<<<257, 512, 0, stream>>>(As, Af, Em, out);
}

// Round 10
// 1265.279 us; speedup vs baseline: 2.8581x; 2.8229x over previous
//
#include <hip/hip_runtime.h>

typedef __attribute__((ext_vector_type(8)))  short  s16x8;
typedef __attribute__((ext_vector_type(8)))  __bf16 bf16x8;
typedef __attribute__((ext_vector_type(16))) float  f32x16;
typedef __attribute__((ext_vector_type(4)))  unsigned int u32x4;

#define EPSF 1e-36f

static __device__ __forceinline__ f32x16 MFMA(s16x8 a, s16x8 b, f32x16 c) {
  return __builtin_amdgcn_mfma_f32_32x32x16_bf16(
      __builtin_bit_cast(bf16x8, a), __builtin_bit_cast(bf16x8, b), c, 0, 0, 0);
}

static __device__ __forceinline__ short f2bf(float f) {
  unsigned u = __builtin_bit_cast(unsigned, f);
  u = (u + 0x7FFFu + ((u >> 16) & 1u)) >> 16;
  return (short)u;
}

static __device__ __forceinline__ unsigned pkf(float a, float b) {
  return (unsigned)(unsigned short)f2bf(a) | ((unsigned)(unsigned short)f2bf(b) << 16);
}

// D (C/D layout: col=lane&31, row=(reg&3)+8*(reg>>2)+4h) -> two k-chunk bf16
// operand fragments (slot t of chunk kk = matrix[16kk+8h+t][c31]); in-register
// pack + half-swap via lane^32. PROVEN R6/R8/R9.
static __device__ __forceinline__ void redistR(const f32x16 d, float sc, int h,
                                               s16x8& f0, s16x8& f1) {
  unsigned pk[8];
#pragma unroll
  for (int q = 0; q < 8; ++q) pk[q] = pkf(d[2 * q] * sc, d[2 * q + 1] * sc);
  unsigned s0 = h ? pk[0] : pk[2];
  unsigned s1 = h ? pk[1] : pk[3];
  unsigned s2 = h ? pk[4] : pk[6];
  unsigned s3 = h ? pk[5] : pk[7];
  unsigned r0 = (unsigned)__shfl_xor((int)s0, 32);
  unsigned r1 = (unsigned)__shfl_xor((int)s1, 32);
  unsigned r2 = (unsigned)__shfl_xor((int)s2, 32);
  unsigned r3 = (unsigned)__shfl_xor((int)s3, 32);
  u32x4 a, b;
  a.x = h ? r0 : pk[0]; a.y = h ? r1 : pk[1]; a.z = h ? pk[2] : r0; a.w = h ? pk[3] : r1;
  b.x = h ? r2 : pk[4]; b.y = h ? r3 : pk[5]; b.z = h ? pk[6] : r2; b.w = h ? pk[7] : r3;
  f0 = __builtin_bit_cast(s16x8, a);
  f1 = __builtin_bit_cast(s16x8, b);
}

// flat step sig in [0,368): 16 groups of (big site: 16 m-steps, 7 small sites: 1 step)
static __device__ __forceinline__ void decodeStep(int sig, int& site, int& m, int& off) {
  int g = sig / 23, o = sig - g * 23;
  if (o < 16) { site = 8 * g; m = o; off = g * 376832 + o * 16384; }
  else { site = 8 * g + (o - 15); m = 0; off = g * 376832 + 262144 + (o - 16) * 16384; }
}

// ---------------- prep: embedding table Em[site][n][16] (f32) ----------------
extern "C" __global__ void prep_emb_k(const float* __restrict__ x, float* __restrict__ Em) {
  int id = blockIdx.x * 256 + threadIdx.x;
  int site = id >> 10, n = id & 1023;
  float x0 = x[(n * 128 + site) * 2 + 0];
  float x1 = x[(n * 128 + site) * 2 + 1];
  const float P5 = 1.57079632679f, P25 = 0.785398163397f, R = 0.70710678118f;
  float u[4] = {sinf(P5 * x0) * R, cosf(P5 * x0) * R, sinf(P25 * x0) * R, cosf(P25 * x0) * R};
  float v[4] = {sinf(P5 * x1) * R, cosf(P5 * x1) * R, sinf(P25 * x1) * R, cosf(P25 * x1) * R};
#pragma unroll
  for (int a = 0; a < 4; ++a) {
    float4 o;
    o.x = u[a] * v[0]; o.y = u[a] * v[1]; o.z = u[a] * v[2]; o.w = u[a] * v[3];
    *(float4*)&Em[id * 16 + a * 4] = o;
  }
}

// ---------------- prep: weights -> As [m][r][e][l] (partition) + As2 [m][l][r][e] (main) ----------------
extern "C" __global__ void prep_w_k(const float* __restrict__ wb, const float* __restrict__ wsm,
                                    short* __restrict__ As, short* __restrict__ As2) {
  int site = blockIdx.x;
  bool big = (site & 7) == 0;
  int nE = big ? 262144 : 16384;
  int nb = (site + 7) >> 3;
  int bs = nb * 262144 + (site - nb) * 16384;
  int kb = site >> 3;
  int ksm = site - kb - 1;
  for (int i = threadIdx.x; i < nE; i += 256) {
    int e = i & 15, r = (i >> 4) & 31, l = (i >> 9) & 31, m = i >> 14;
    float val = big ? wb[(((kb * 32 + l) * 16 + e) * 16 + m) * 32 + r]
                    : wsm[((ksm * 32 + l) * 16 + e) * 32 + r];
    if (site == 0 && l != 0) val = 0.f;
    if (site == 127 && r != 0) val = 0.f;
    short bv = f2bf(val);
    As2[bs + i] = bv;                                      // [m][l][r][e]
    As[bs + ((m * 32 + r) * 16 + e) * 32 + l] = bv;        // [m][r][e][l]
  }
}

// ---------------- main: blocks 0..255 = 4 samples, block 256 = partition ----------------
extern "C" __global__ void __launch_bounds__(256, 1)
tn_main(const short* __restrict__ As, const short* __restrict__ As2,
        const float* __restrict__ Em, float* __restrict__ out) {
  // slice 32KB @0 (XOR-swizzled granules), B-area 8KB @32768; partition aliases for reduce
  __shared__ __align__(16) char smem[40960];
  const int tid = threadIdx.x;
  const int lane = tid & 63;
  const int w = tid >> 6;
  const int c31 = lane & 31;
  const int h = lane >> 5;
  const f32x16 Z = {0.f,0.f,0.f,0.f,0.f,0.f,0.f,0.f,0.f,0.f,0.f,0.f,0.f,0.f,0.f,0.f};

  if (blockIdx.x < 256) {
    // ======== sample blocks: wave = sample (consumer) + 8 B-form tiles (producer) ========
    const int n0 = blockIdx.x * 4;
    s16x8 Mf0 = {0,0,0,0,0,0,0,0}, Mf1 = {0,0,0,0,0,0,0,0};
    if (lane == 0) Mf0[0] = (short)0x3F80;   // M_init = e0 e0^T
    f32x16 Macc = Z;
    float log_norm = 0.f;
    s16x8 Ef = {0,0,0,0,0,0,0,0};

    // stage slice of step sig2: linear LDS dest, inverse-swizzled global source
    auto stage = [&](int sig2) {
      int st2, m2, off2; decodeStep(sig2, st2, m2, off2);
      const char* src = (const char*)As2 + (size_t)off2 * 2;
#pragma unroll
      for (int k = 0; k < 8; ++k) {
        int GL = (k * 4 + w) * 64 + lane;                      // dest granule (16B)
        int gs = (GL & ~63) | ((GL & 63) ^ ((GL >> 6) & 7));   // logical source granule
        __builtin_amdgcn_global_load_lds((const unsigned int*)(src + gs * 16),
                                         (unsigned int*)(smem + (k * 4 + w) * 1024),
                                         16, 0, 0);
      }
    };

    stage(0);
    __syncthreads();

#pragma unroll 1
    for (int sig = 0; sig < 368; ++sig) {
      int site, m, off; decodeStep(sig, site, m, off); (void)off;

      // ---- E fragments at site start (lane c31 = sample index; rows >=4 zero) ----
      if (m == 0) {
        float4 q0 = {0.f,0.f,0.f,0.f}, q1 = {0.f,0.f,0.f,0.f};
        if (c31 < 4) {
          const float* ep = Em + ((size_t)site * 1024 + n0 + c31) * 16 + 8 * h;
          q0 = *(const float4*)ep;
          q1 = *(const float4*)(ep + 4);
        }
        u32x4 ef;
        ef.x = pkf(q0.x, q0.y); ef.y = pkf(q0.z, q0.w);
        ef.z = pkf(q1.x, q1.y); ef.w = pkf(q1.z, q1.w);
        Ef = __builtin_bit_cast(s16x8, ef);
      }

      // ---- producer: tiles l = 8w..8w+7 (pairs); D[s][r] = sum_e er_s[e] W[l][e][r] ----
      unsigned* barea = (unsigned*)(smem + 32768);
#pragma unroll
      for (int t = 0; t < 4; ++t) {
        const int lA = 8 * w + 2 * t;
        const int lB = lA + 1;
        s16x8 WA = *(const s16x8*)(smem + lA * 1024 + (((c31 * 2 + h) ^ (lA & 7)) << 4));
        s16x8 WB = *(const s16x8*)(smem + lB * 1024 + (((c31 * 2 + h) ^ (lB & 7)) << 4));
        f32x16 DA = MFMA(Ef, WA, Z);
        f32x16 DB = MFMA(Ef, WB, Z);
        if (h == 0) {                       // rows 0-3 (= samples) live in h=0 regs 0-3
          const int pr = (4 * w + t) ^ (c31 & 15);
#pragma unroll
          for (int q = 0; q < 4; ++q)
            barea[q * 512 + c31 * 16 + pr] = pkf(DA[q], DB[q]);
        }
      }
      __syncthreads();                       // B visible; all slice ds_reads done

      if (sig + 1 < 368) stage(sig + 1);     // safe: slice reads drained by barrier

      // ---- consumer: sample n = n0 + w ----
      const unsigned* ba = (const unsigned*)(smem + 32768) + w * 512 + c31 * 16;
      u32x4 b0v, b1v;
#pragma unroll
      for (int i = 0; i < 4; ++i) ((unsigned*)&b0v)[i] = ba[(4 * h + i) ^ (c31 & 15)];
#pragma unroll
      for (int i = 0; i < 4; ++i) ((unsigned*)&b1v)[i] = ba[(8 + 4 * h + i) ^ (c31 & 15)];
      s16x8 c0 = __builtin_bit_cast(s16x8, b0v);
      s16x8 c1 = __builtin_bit_cast(s16x8, b1v);

      f32x16 D1 = MFMA(Mf0, c0, Z);
      D1 = MFMA(Mf1, c1, D1);
      s16x8 Cf0, Cf1;
      redistR(D1, 1.f, h, Cf0, Cf1);
      if (m == 0) Macc = Z;
      Macc = MFMA(c0, Cf0, Macc);
      Macc = MFMA(c1, Cf1, Macc);

      bool lastM = (m == (((site & 7) == 0) ? 15 : 0));
      if (lastM) {
        if (site < 127) {
          float s = fabsf(Macc[0]);
#pragma unroll
          for (int j = 1; j < 16; ++j) s = fmaxf(s, fabsf(Macc[j]));
#pragma unroll
          for (int off2 = 32; off2 >= 1; off2 >>= 1) s = fmaxf(s, __shfl_xor(s, off2));
          float inv = 1.f / (s + EPSF);
          log_norm += logf(s + EPSF);
          redistR(Macc, inv, h, Mf0, Mf1);
        } else {
          if (lane == 0) out[n0 + w] = logf(fmaxf(Macc[0], 0.f) + EPSF) + log_norm;
        }
      }
      __syncthreads();   // B reads done; staged loads drained (vmcnt before barrier)
    }
  } else {
    // ======== partition chain (log_Z): 1 block, 4 waves x 4 e (R6-proven) ========
    float* red = (float*)smem;            // [4 waves][32*33] f32 = 16.9KB
    s16x8 Mf0 = {0,0,0,0,0,0,0,0}, Mf1 = {0,0,0,0,0,0,0,0};
    if (lane == 0) Mf0[0] = (short)0x3F80;
    f32x16 Macc = Z;
    float log_norm = 0.f;
#pragma unroll 1
    for (int sig = 0; sig < 368; ++sig) {
      int site, m, off; decodeStep(sig, site, m, off);
      if (m == 0) Macc = Z;
      s16x8 pa[4], pb[4];
#pragma unroll
      for (int q = 0; q < 4; ++q) {
        int e = 4 * w + q;
        const short* ap = As + off + (c31 * 16 + e) * 32;
        pa[q] = *(const s16x8*)(ap + 8 * h);
        pb[q] = *(const s16x8*)(ap + 16 + 8 * h);
      }
#pragma unroll
      for (int q = 0; q < 4; ++q) {
        f32x16 D1 = MFMA(Mf0, pa[q], Z);
        D1 = MFMA(Mf1, pb[q], D1);
        s16x8 Cf0, Cf1;
        redistR(D1, 1.f, h, Cf0, Cf1);
        Macc = MFMA(pa[q], Cf0, Macc);
        Macc = MFMA(pb[q], Cf1, Macc);
      }
      bool lastM = (m == (((site & 7) == 0) ? 15 : 0));
      if (lastM) {
        float* myr = red + w * 1056;
#pragma unroll
        for (int reg = 0; reg < 16; ++reg) {
          int row = (reg & 3) + 8 * (reg >> 2) + 4 * h;
          myr[row * 33 + c31] = Macc[reg];
        }
        __syncthreads();
        f32x16 tot;
#pragma unroll
        for (int reg = 0; reg < 16; ++reg) {
          int row = (reg & 3) + 8 * (reg >> 2) + 4 * h;
          int idx = row * 33 + c31;
          tot[reg] = red[idx] + red[1056 + idx] + red[2112 + idx] + red[3168 + idx];
        }
        float s = fabsf(tot[0]);
#pragma unroll
        for (int j = 1; j < 16; ++j) s = fmaxf(s, fabsf(tot[j]));
#pragma unroll
        for (int off2 = 32; off2 >= 1; off2 >>= 1) s = fmaxf(s, __shfl_xor(s, off2));
        __syncthreads();   // all reads done before red[] reuse
        if (site < 127) {
          float inv = 1.f / (s + EPSF);
          log_norm += logf(s + EPSF);
          redistR(tot, inv, h, Mf0, Mf1);
        } else {
          if (tid == 0) out[1024] = logf(fmaxf(tot[0], 0.f) + EPSF) + log_norm;
        }
      }
    }
  }
}

extern "C" void kernel_launch(void* const* d_in, const int* in_sizes, int n_in,
                              void* d_out, int out_size, void* d_ws, size_t ws_size,
                              hipStream_t stream) {
  (void)in_sizes; (void)n_in; (void)out_size; (void)ws_size;
  const float* x   = (const float*)d_in[0];
  const float* wb  = (const float*)d_in[1];
  const float* wsm = (const float*)d_in[2];
  char* ws = (char*)d_ws;
  short* As  = (short*)ws;                         // 12,058,624 B  [m][r][e][l]
  short* As2 = (short*)(ws + 12058624);            // 12,058,624 B  [m][l][r][e]
  float* Em  = (float*)(ws + 24117248);            //  8,388,608 B
  float* out = (float*)d_out;                      // 1024 logits + log_Z

  prep_emb_k<<<512, 256, 0, stream>>>(x, Em);
  prep_w_k<<<128, 256, 0, stream>>>(wb, wsm, As, As2);
  tn_main<<<257, 256, 0, stream>>>(As, As2, Em, out);
}